// Round 4
// baseline (386.334 us; speedup 1.0000x reference)
//
#include <hip/hip_runtime.h>

#define NUM_USER 200000
#define NUM_EVENT 50000
#define NUM_EDGES 1000000
#define DDIM 64
#define LDP 68  // LDS leading dim for linear tiles

// Bucketed CSR build: user buckets span 2048 nodes, event buckets span 256.
#define NBU 98                 // 98*2048 = 200704 >= NUM_USER
#define NBE 196                // 196*256 = 50176 >= NUM_EVENT
#define NB (NBU + NBE)         // 294
#define CHUNK 8192
#define NCH ((NUM_EDGES + CHUNK - 1) / CHUNK)  // 123

// Fixed bucket capacities (counting-sort without the count/scan passes).
// User bucket count ~ Binomial(1M, 2048/200000): mean 10240, sd ~101 -> 11264 is +10sd.
// Event bucket count ~ Binomial(1M, 256/50000):  mean 5120,  sd ~71  -> 5632 is +7sd.
#define CAPU 11264
#define CAPE 5632

// Linear: dynamic tile pool, grid = exact residency capacity (4 blocks/CU @ 34.8KB LDS)
#define POOL_GRID 1024
#define TU ((NUM_USER + 63) / 64)   // 3125
#define TE ((NUM_EVENT + 63) / 64)  // 782
#define NTILES (TU + TE)

// Gather: persistent grid, phase-sequential (all waves do users, then events)
#define GGRID 2048

// bf16 pair packing: lin tables stored as uint = (bf16(hi)<<16)|bf16(lo).
__device__ __forceinline__ unsigned int pack_bf2(float lo, float hi) {
  unsigned int ul = __float_as_uint(lo);
  unsigned int uh = __float_as_uint(hi);
  ul = (ul + 0x7FFFu + ((ul >> 16) & 1u)) >> 16;
  uh = (uh + 0x7FFFu + ((uh >> 16) & 1u)) & 0xFFFF0000u;
  return uh | ul;
}
__device__ __forceinline__ float bf_lo(unsigned int v) { return __uint_as_float(v << 16); }
__device__ __forceinline__ float bf_hi(unsigned int v) { return __uint_as_float(v & 0xFFFF0000u); }

// ---------------- Scatter: single pass, fixed-capacity buckets ----------------
// itemU = (dst&2047)<<16 | src ; itemE = (src&255)<<18 | dst
__global__ __launch_bounds__(256) void bucket_scatter_kernel(
    const int* __restrict__ src, const int* __restrict__ dst,
    int* __restrict__ cntU, int* __restrict__ cntE,
    unsigned int* __restrict__ itemsU, unsigned int* __restrict__ itemsE) {
  __shared__ int cnt[NB];
  __shared__ int cur[NB];
  for (int i = threadIdx.x; i < NB; i += 256) cnt[i] = 0;
  __syncthreads();
  const int e0 = blockIdx.x * CHUNK;
  const int e1 = min(e0 + CHUNK, NUM_EDGES);
  for (int i = e0 + threadIdx.x; i < e1; i += 256) {
    atomicAdd(&cnt[dst[i] >> 11], 1);
    atomicAdd(&cnt[NBU + (src[i] >> 8)], 1);
  }
  __syncthreads();
  for (int i = threadIdx.x; i < NB; i += 256) {
    int c = cnt[i];
    if (c) {
      if (i < NBU)
        cur[i] = i * CAPU + atomicAdd(&cntU[i], c);
      else
        cur[i] = (i - NBU) * CAPE + atomicAdd(&cntE[i - NBU], c);
    } else {
      cur[i] = 0;
    }
  }
  __syncthreads();
  for (int i = e0 + threadIdx.x; i < e1; i += 256) {
    const int s = src[i];
    const int d = dst[i];
    int r = atomicAdd(&cur[d >> 11], 1);
    itemsU[r] = ((unsigned int)(d & 2047) << 16) | (unsigned int)s;
    int r2 = atomicAdd(&cur[NBU + (s >> 8)], 1);
    itemsE[r2] = ((unsigned int)(s & 255) << 18) | (unsigned int)d;
  }
}

// ---------------- Pass B bodies (share a union'd LDS buffer) ----------------

// user: one block per bucket of 2048 users. smem needs 2048+256 ints = 9216 B.
__device__ __forceinline__ void build_user_body(
    unsigned char* smem, const int* __restrict__ cntU,
    const unsigned int* __restrict__ itemsU, int* __restrict__ offs,
    unsigned short* __restrict__ lists_u, int b) {
  int* cnt = (int*)smem;       // 2048
  int* part = cnt + 2048;      // 256
  const int istart = b * CAPU;
  const int iend = istart + cntU[b];
  const int tid = threadIdx.x;
  for (int i = tid; i < 2048; i += 256) cnt[i] = 0;
  __syncthreads();
  for (int i = istart + tid; i < iend; i += 256)
    atomicAdd(&cnt[itemsU[i] >> 16], 1);
  __syncthreads();
  int v[8];
  int sum = 0;
#pragma unroll
  for (int j = 0; j < 8; ++j) {
    v[j] = cnt[tid * 8 + j];
    sum += v[j];
  }
  part[tid] = sum;
  __syncthreads();
  for (int off = 1; off < 256; off <<= 1) {
    int t = (tid >= off) ? part[tid - off] : 0;
    __syncthreads();
    part[tid] += t;
    __syncthreads();
  }
  int run = (tid == 0) ? 0 : part[tid - 1];
  const int node0 = b * 2048;
#pragma unroll
  for (int j = 0; j < 8; ++j) {
    const int n = node0 + tid * 8 + j;
    if (n < NUM_USER) offs[n] = istart + run + v[j];  // END position (padded space)
    cnt[tid * 8 + j] = run;                           // exclusive -> cursor
    run += v[j];
  }
  __syncthreads();
  for (int i = istart + tid; i < iend; i += 256) {
    const unsigned int it = itemsU[i];
    int r = atomicAdd(&cnt[it >> 16], 1);
    lists_u[istart + r] = (unsigned short)(it & 0xFFFFu);
  }
}

// event: one block per bucket of 256 events. smem needs 512 ints = 2048 B.
__device__ __forceinline__ void build_event_body(
    unsigned char* smem, const int* __restrict__ cntE,
    const unsigned int* __restrict__ itemsE, int* __restrict__ offs,
    int* __restrict__ lists_e, int b) {
  int* cnt = (int*)smem;   // 256
  int* s2 = cnt + 256;     // 256
  const int istart = b * CAPE;
  const int iend = istart + cntE[b];
  const int tid = threadIdx.x;
  cnt[tid] = 0;
  __syncthreads();
  for (int i = istart + tid; i < iend; i += 256)
    atomicAdd(&cnt[itemsE[i] >> 18], 1);
  __syncthreads();
  const int v = cnt[tid];
  s2[tid] = v;
  __syncthreads();
  for (int off = 1; off < 256; off <<= 1) {
    int t = (tid >= off) ? s2[tid - off] : 0;
    __syncthreads();
    s2[tid] += t;
    __syncthreads();
  }
  const int excl = s2[tid] - v;
  const int e0 = b * 256;
  if (e0 + tid < NUM_EVENT)
    offs[NUM_USER + e0 + tid] = istart + excl + v;  // END position (padded space)
  cnt[tid] = excl;
  __syncthreads();
  for (int i = istart + tid; i < iend; i += 256) {
    const unsigned int it = itemsE[i];
    int r = atomicAdd(&cnt[it >> 18], 1);
    lists_e[istart + r] = (int)(it & 0x3FFFFu);
  }
}

// ---------------- Fused linear: y = x @ W^T + b, fp32 in, bf16-packed out ----------------
// Dynamic tile pool: tiles popped from a global atomic counter. Tile t < TU is a
// user tile; else event tile. W/bias restaged only on table switch (monotone pops
// mean at most one switch per block). smem: 2 * 64*LDP floats = 34816 B.

__device__ __forceinline__ void linear_pool(
    unsigned char* smem, int* s_tile, int* __restrict__ tcnt,
    const float* __restrict__ xu, const float* __restrict__ Wu,
    const float* __restrict__ bu, unsigned int* __restrict__ yu,
    const float* __restrict__ xe, const float* __restrict__ We,
    const float* __restrict__ be, unsigned int* __restrict__ ye) {
  float* xT = (float*)smem;       // xT[k][r]
  float* wT = xT + 64 * LDP;      // wT[k][c] = W[c][k]
  const int tid = threadIdx.x;
  const int r64 = tid & 63;
  const int q = tid >> 6;
  const int cg = tid & 15;  // cols cg*4..cg*4+3
  const int rg = tid >> 4;  // rows rg*4..rg*4+3

  int cur_tab = -1;
  float4 bv = make_float4(0.f, 0.f, 0.f, 0.f);

  for (;;) {
    __syncthreads();  // (A) prior-iter compute done; s_tile/xT/wT reusable
    if (tid == 0) *s_tile = atomicAdd(tcnt, 1);
    __syncthreads();  // (B) s_tile visible
    const int t = *s_tile;
    if (t >= NTILES) break;

    const int tab = (t < TU) ? 0 : 1;
    const float* x;
    const float* W;
    const float* bias;
    unsigned int* y;
    int n, tloc;
    if (tab == 0) {
      x = xu; W = Wu; bias = bu; y = yu; n = NUM_USER; tloc = t;
    } else {
      x = xe; W = We; bias = be; y = ye; n = NUM_EVENT; tloc = t - TU;
    }

    if (tab != cur_tab) {  // Stage W^T (at most twice per block).
      const int c = r64;
      const float4* wr = reinterpret_cast<const float4*>(W + (size_t)c * DDIM);
#pragma unroll
      for (int i = 0; i < 4; ++i) {
        const int kc4 = q * 4 + i;
        float4 tv = wr[kc4];
        wT[(kc4 * 4 + 0) * LDP + c] = tv.x;
        wT[(kc4 * 4 + 1) * LDP + c] = tv.y;
        wT[(kc4 * 4 + 2) * LDP + c] = tv.z;
        wT[(kc4 * 4 + 3) * LDP + c] = tv.w;
      }
      bv = reinterpret_cast<const float4*>(bias)[cg];
      cur_tab = tab;
    }

    const int row0 = tloc * 64;
    const int nrows = min(64, n - row0);
    {
      const int r = r64;
      if (r < nrows) {
        const float4* xr = reinterpret_cast<const float4*>(x + (size_t)(row0 + r) * DDIM);
#pragma unroll
        for (int i = 0; i < 4; ++i) {
          const int kc4 = q * 4 + i;
          float4 tv = xr[kc4];
          xT[(kc4 * 4 + 0) * LDP + r] = tv.x;
          xT[(kc4 * 4 + 1) * LDP + r] = tv.y;
          xT[(kc4 * 4 + 2) * LDP + r] = tv.z;
          xT[(kc4 * 4 + 3) * LDP + r] = tv.w;
        }
      }
    }
    __syncthreads();  // (C) tiles staged

    float acc[4][4];
#pragma unroll
    for (int i = 0; i < 4; ++i) {
      acc[i][0] = bv.x; acc[i][1] = bv.y; acc[i][2] = bv.z; acc[i][3] = bv.w;
    }
#pragma unroll 8
    for (int k = 0; k < 64; ++k) {
      const float4 xv = *reinterpret_cast<const float4*>(&xT[k * LDP + rg * 4]);
      const float4 wv = *reinterpret_cast<const float4*>(&wT[k * LDP + cg * 4]);
      const float xa[4] = {xv.x, xv.y, xv.z, xv.w};
      const float wa[4] = {wv.x, wv.y, wv.z, wv.w};
#pragma unroll
      for (int i = 0; i < 4; ++i)
#pragma unroll
        for (int j = 0; j < 4; ++j) acc[i][j] += xa[i] * wa[j];
    }
#pragma unroll
    for (int i = 0; i < 4; ++i) {
      const int r = rg * 4 + i;
      if (r < nrows) {
        uint2 o = make_uint2(pack_bf2(acc[i][0], acc[i][1]),
                             pack_bf2(acc[i][2], acc[i][3]));
        reinterpret_cast<uint2*>(y + (size_t)(row0 + r) * 32)[cg] = o;
      }
    }
  }
}

// Merged dispatch: CSR pass-B (294 blocks) + layer-1 linear tile pool.
// Build blocks join the pool when done; grid = exact residency capacity.
__global__ __launch_bounds__(256) void build_lin_kernel(
    const int* __restrict__ cntU, const int* __restrict__ cntE,
    const unsigned int* __restrict__ itemsU,
    const unsigned int* __restrict__ itemsE, int* __restrict__ offs,
    unsigned short* __restrict__ lists_u, int* __restrict__ lists_e,
    int* __restrict__ tcnt,
    const float* __restrict__ xu, const float* __restrict__ Wu,
    const float* __restrict__ bu, unsigned int* __restrict__ yu,
    const float* __restrict__ xe, const float* __restrict__ We,
    const float* __restrict__ be, unsigned int* __restrict__ ye) {
  __shared__ __align__(16) unsigned char smem[64 * LDP * 2 * sizeof(float)];
  __shared__ int s_tile;
  const int bx = blockIdx.x;
  if (bx < NBU) {
    build_user_body(smem, cntU, itemsU, offs, lists_u, bx);
  } else if (bx < NB) {
    build_event_body(smem, cntE, itemsE, offs, lists_e, bx - NBU);
  }
  linear_pool(smem, &s_tile, tcnt, xu, Wu, bu, yu, xe, We, be, ye);
}

// Layer-2 linear (standalone, depends on gather-1 output).
__global__ __launch_bounds__(256) void linear_pool_kernel(
    int* __restrict__ tcnt,
    const float* __restrict__ xu, const float* __restrict__ Wu,
    const float* __restrict__ bu, unsigned int* __restrict__ yu,
    const float* __restrict__ xe, const float* __restrict__ We,
    const float* __restrict__ be, unsigned int* __restrict__ ye) {
  __shared__ __align__(16) unsigned char smem[64 * LDP * 2 * sizeof(float)];
  __shared__ int s_tile;
  linear_pool(smem, &s_tile, tcnt, xu, Wu, bu, yu, xe, We, be, ye);
}

// ---------------- Fused gather aggregation (phase-sequential, prefetched) ----------------
// Eighth-wave (8 lanes) per node; lane dl holds dims 8dl..8dl+7 as one uint4.
// offs are END positions in padded item-space; the first node of each bucket
// starts at the bucket base (b*CAP), not at the previous node's end.
__device__ __forceinline__ void seg_bounds(
    const int* __restrict__ offs, int obase, int node, int shift, int cap,
    int& s, int& e) {
  e = offs[obase + node];
  const int ib = node & ((1 << shift) - 1);
  s = (ib == 0) ? (node >> shift) * cap : offs[obase + node - 1];
}

template <typename IdxT>
__device__ __forceinline__ void gather_phase(
    const int* __restrict__ offs, const IdxT* __restrict__ lists,
    const uint4* __restrict__ lin_self, const uint4* __restrict__ lin_other,
    float4* __restrict__ out, int n, int obase, int shift, int cap,
    int stream_id, int nstreams, int dl) {
  int node = stream_id;
  if (node >= n) return;
  int start, end;
  seg_bounds(offs, obase, node, shift, cap, start, end);
  uint4 sv = lin_self[(size_t)node * 8 + dl];

  while (true) {
    // Prefetch next node's descriptors (issued before the gather chain).
    const int nnode = node + nstreams;
    int nstart = 0, nend = 0;
    uint4 nsv = make_uint4(0u, 0u, 0u, 0u);
    if (nnode < n) {
      seg_bounds(offs, obase, nnode, shift, cap, nstart, nend);
      nsv = lin_self[(size_t)nnode * 8 + dl];
    }

    float a0 = bf_lo(sv.x), a1 = bf_hi(sv.x);
    float a2 = bf_lo(sv.y), a3 = bf_hi(sv.y);
    float a4 = bf_lo(sv.z), a5 = bf_hi(sv.z);
    float a6 = bf_lo(sv.w), a7 = bf_hi(sv.w);
    int j = start;
    for (; j + 4 <= end; j += 4) {
      int o[4];
#pragma unroll
      for (int t = 0; t < 4; ++t) o[t] = (int)lists[j + t];
      uint4 v[4];
#pragma unroll
      for (int t = 0; t < 4; ++t) v[t] = lin_other[(size_t)o[t] * 8 + dl];
#pragma unroll
      for (int t = 0; t < 4; ++t) {
        a0 += bf_lo(v[t].x); a1 += bf_hi(v[t].x);
        a2 += bf_lo(v[t].y); a3 += bf_hi(v[t].y);
        a4 += bf_lo(v[t].z); a5 += bf_hi(v[t].z);
        a6 += bf_lo(v[t].w); a7 += bf_hi(v[t].w);
      }
    }
    for (; j < end; ++j) {
      const int o0 = (int)lists[j];
      const uint4 v0 = lin_other[(size_t)o0 * 8 + dl];
      a0 += bf_lo(v0.x); a1 += bf_hi(v0.x);
      a2 += bf_lo(v0.y); a3 += bf_hi(v0.y);
      a4 += bf_lo(v0.z); a5 += bf_hi(v0.z);
      a6 += bf_lo(v0.w); a7 += bf_hi(v0.w);
    }
    const float inv = 1.0f / (float)(end - start + 1);
    out[(size_t)node * 16 + dl * 2] =
        make_float4(a0 * inv, a1 * inv, a2 * inv, a3 * inv);
    out[(size_t)node * 16 + dl * 2 + 1] =
        make_float4(a4 * inv, a5 * inv, a6 * inv, a7 * inv);

    if (nnode >= n) break;
    node = nnode;
    start = nstart;
    end = nend;
    sv = nsv;
  }
}

__global__ __launch_bounds__(256) void gather_fused_kernel(
    const int* __restrict__ offs, const unsigned short* __restrict__ lists_u,
    const int* __restrict__ lists_e, const unsigned int* __restrict__ lin_u,
    const unsigned int* __restrict__ lin_e, float* __restrict__ out_u,
    float* __restrict__ out_e) {
  const int lane = threadIdx.x & 63;
  const int dl = lane & 7;
  const int ew = ((blockIdx.x * (blockDim.x >> 6) + (threadIdx.x >> 6)) << 3) |
                 (lane >> 3);               // global eighth-wave id
  const int nstreams = GGRID * 32;          // 65536 streams, both phases
  gather_phase<unsigned short>(
      offs, lists_u, reinterpret_cast<const uint4*>(lin_u),
      reinterpret_cast<const uint4*>(lin_e), reinterpret_cast<float4*>(out_u),
      NUM_USER, 0, 11, CAPU, ew, nstreams, dl);
  gather_phase<int>(
      offs, lists_e, reinterpret_cast<const uint4*>(lin_e),
      reinterpret_cast<const uint4*>(lin_u), reinterpret_cast<float4*>(out_e),
      NUM_EVENT, NUM_USER, 8, CAPE, ew, nstreams, dl);
}

// ---------------- Launch ----------------

extern "C" void kernel_launch(void* const* d_in, const int* in_sizes, int n_in,
                              void* d_out, int out_size, void* d_ws,
                              size_t ws_size, hipStream_t stream) {
  const float* x_user = (const float*)d_in[0];
  const float* x_event = (const float*)d_in[1];
  const int* src = (const int*)d_in[2];
  const int* dst = (const int*)d_in[3];
  const float* Wu0 = (const float*)d_in[4];
  const float* bu0 = (const float*)d_in[5];
  const float* We0 = (const float*)d_in[6];
  const float* be0 = (const float*)d_in[7];
  const float* Wu1 = (const float*)d_in[8];
  const float* bu1 = (const float*)d_in[9];
  const float* We1 = (const float*)d_in[10];
  const float* be1 = (const float*)d_in[11];

  // Workspace layout (39.6 MB, strictly below the proven-safe 47 MB of R0-R2).
  unsigned int* lin_u = (unsigned int*)d_ws;            // 6.4M u32 = 25.6 MB
  unsigned int* lin_e = lin_u + (size_t)NUM_USER * 32;  // 1.6M u32 = 6.4 MB
  int* offs = (int*)(lin_e + (size_t)NUM_EVENT * 32);   // 250,000 = 1.0 MB
  int* cntU = offs + (NUM_USER + NUM_EVENT);            // 98
  int* cntE = cntU + NBU;                               // 196
  int* tc = cntE + NBE;                                 // 2 (tile-pool counters)
  int* lists_e = (int*)(tc + 2);                        // NBE*CAPE int = 4.42 MB
  unsigned short* lists_u =
      (unsigned short*)(lists_e + (size_t)NBE * CAPE);  // NBU*CAPU u16 = 2.21 MB

  // items buffers overlay d_out (64 MB): they are consumed entirely inside
  // build_lin_kernel, which completes (stream order) before gather-1 writes out.
  unsigned int* itemsU = (unsigned int*)d_out;          // NBU*CAPU u32 = 4.42 MB
  unsigned int* itemsE = itemsU + (size_t)NBU * CAPU;   // NBE*CAPE u32 = 4.42 MB

  float* out_u = (float*)d_out;
  float* out_e = out_u + (size_t)NUM_USER * DDIM;

  // Zero all counters (bucket counts + 2 tile-pool counters) in one memset.
  hipMemsetAsync(cntU, 0, (NBU + NBE + 2) * sizeof(int), stream);

  // --- CSR scatter (single pass, fixed-capacity buckets) ---
  bucket_scatter_kernel<<<NCH, 256, 0, stream>>>(src, dst, cntU, cntE, itemsU,
                                                 itemsE);

  // ---- CSR pass-B + Layer-1 linear (merged, dynamic tile pool) ----
  build_lin_kernel<<<POOL_GRID, 256, 0, stream>>>(
      cntU, cntE, itemsU, itemsE, offs, lists_u, lists_e, tc,
      x_user, Wu0, bu0, lin_u, x_event, We0, be0, lin_e);
  gather_fused_kernel<<<GGRID, 256, 0, stream>>>(
      offs, lists_u, lists_e, lin_u, lin_e, out_u, out_e);

  // ---- Layer 2 ----
  linear_pool_kernel<<<POOL_GRID, 256, 0, stream>>>(
      tc + 1, out_u, Wu1, bu1, lin_u, out_e, We1, be1, lin_e);
  gather_fused_kernel<<<GGRID, 256, 0, stream>>>(
      offs, lists_u, lists_e, lin_u, lin_e, out_u, out_e);
}

// Round 5
// 336.124 us; speedup vs baseline: 1.1494x; 1.1494x over previous
//
#include <hip/hip_runtime.h>

#define NUM_USER 200000
#define NUM_EVENT 50000
#define NUM_EDGES 1000000
#define DDIM 64
#define LDP 64  // LDS leading dim; no pad needed (reads are broadcast / 2-way)

// Bucketed CSR build: user buckets span 2048 nodes, event buckets span 256.
#define NBU 98                 // 98*2048 = 200704 >= NUM_USER
#define NBE 196                // 196*256 = 50176 >= NUM_EVENT
#define NB (NBU + NBE)         // 294
#define CHUNK 2048
#define NCH ((NUM_EDGES + CHUNK - 1) / CHUNK)  // 489

// Fixed bucket capacities (counting-sort without count/scan passes).
// User bucket ~ Binomial(1M, 2048/200000): mean 10240, sd ~101 -> 11264 = +10sd.
// Event bucket ~ Binomial(1M, 256/50000):  mean 5120,  sd ~71  -> 5632  = +7sd.
#define CAPU 11264
#define CAPE 5632

// Linear: static stride over unified tile list; grid = exact residency.
// LDS 32768 B -> 5 blocks/CU -> 1280 co-resident blocks, zero tail.
#define BL_GRID 1280
#define TU ((NUM_USER + 63) / 64)   // 3125
#define TE ((NUM_EVENT + 63) / 64)  // 782
#define NTILES (TU + TE)            // 3907

// Gather: persistent grid, phase-sequential
#define GGRID 2048

// bf16 pair packing: lin tables stored as uint = (bf16(hi)<<16)|bf16(lo).
__device__ __forceinline__ unsigned int pack_bf2(float lo, float hi) {
  unsigned int ul = __float_as_uint(lo);
  unsigned int uh = __float_as_uint(hi);
  ul = (ul + 0x7FFFu + ((ul >> 16) & 1u)) >> 16;
  uh = (uh + 0x7FFFu + ((uh >> 16) & 1u)) & 0xFFFF0000u;
  return uh | ul;
}
__device__ __forceinline__ float bf_lo(unsigned int v) { return __uint_as_float(v << 16); }
__device__ __forceinline__ float bf_hi(unsigned int v) { return __uint_as_float(v & 0xFFFF0000u); }

// ---------------- Scatter: single pass, fixed-capacity buckets ----------------
// itemU = (dst&2047)<<16 | src ; itemE = (src&255)<<18 | dst
__global__ __launch_bounds__(256) void bucket_scatter_kernel(
    const int* __restrict__ src, const int* __restrict__ dst,
    int* __restrict__ cntU, int* __restrict__ cntE,
    unsigned int* __restrict__ itemsU, unsigned int* __restrict__ itemsE) {
  __shared__ int cnt[NB];
  __shared__ int cur[NB];
  for (int i = threadIdx.x; i < NB; i += 256) cnt[i] = 0;
  __syncthreads();
  const int e0 = blockIdx.x * CHUNK;
  const int e1 = min(e0 + CHUNK, NUM_EDGES);
  for (int i = e0 + threadIdx.x; i < e1; i += 256) {
    atomicAdd(&cnt[dst[i] >> 11], 1);
    atomicAdd(&cnt[NBU + (src[i] >> 8)], 1);
  }
  __syncthreads();
  for (int i = threadIdx.x; i < NB; i += 256) {
    int c = cnt[i];
    if (c) {
      if (i < NBU)
        cur[i] = i * CAPU + atomicAdd(&cntU[i], c);
      else
        cur[i] = (i - NBU) * CAPE + atomicAdd(&cntE[i - NBU], c);
    } else {
      cur[i] = 0;
    }
  }
  __syncthreads();
  for (int i = e0 + threadIdx.x; i < e1; i += 256) {
    const int s = src[i];
    const int d = dst[i];
    int r = atomicAdd(&cur[d >> 11], 1);
    itemsU[r] = ((unsigned int)(d & 2047) << 16) | (unsigned int)s;
    int r2 = atomicAdd(&cur[NBU + (s >> 8)], 1);
    itemsE[r2] = ((unsigned int)(s & 255) << 18) | (unsigned int)d;
  }
}

// ---------------- Pass B bodies (share a union'd LDS buffer) ----------------

// user: one block per bucket of 2048 users. smem needs 2048+256 ints = 9216 B.
__device__ __forceinline__ void build_user_body(
    unsigned char* smem, const int* __restrict__ cntU,
    const unsigned int* __restrict__ itemsU, int* __restrict__ offs,
    unsigned short* __restrict__ lists_u, int b) {
  int* cnt = (int*)smem;       // 2048
  int* part = cnt + 2048;      // 256
  const int istart = b * CAPU;
  const int iend = istart + cntU[b];
  const int tid = threadIdx.x;
  for (int i = tid; i < 2048; i += 256) cnt[i] = 0;
  __syncthreads();
  for (int i = istart + tid; i < iend; i += 256)
    atomicAdd(&cnt[itemsU[i] >> 16], 1);
  __syncthreads();
  int v[8];
  int sum = 0;
#pragma unroll
  for (int j = 0; j < 8; ++j) {
    v[j] = cnt[tid * 8 + j];
    sum += v[j];
  }
  part[tid] = sum;
  __syncthreads();
  for (int off = 1; off < 256; off <<= 1) {
    int t = (tid >= off) ? part[tid - off] : 0;
    __syncthreads();
    part[tid] += t;
    __syncthreads();
  }
  int run = (tid == 0) ? 0 : part[tid - 1];
  const int node0 = b * 2048;
#pragma unroll
  for (int j = 0; j < 8; ++j) {
    const int n = node0 + tid * 8 + j;
    if (n < NUM_USER) offs[n] = istart + run + v[j];  // END position (padded space)
    cnt[tid * 8 + j] = run;                           // exclusive -> cursor
    run += v[j];
  }
  __syncthreads();
  for (int i = istart + tid; i < iend; i += 256) {
    const unsigned int it = itemsU[i];
    int r = atomicAdd(&cnt[it >> 16], 1);
    lists_u[istart + r] = (unsigned short)(it & 0xFFFFu);
  }
}

// event: one block per bucket of 256 events. smem needs 512 ints = 2048 B.
__device__ __forceinline__ void build_event_body(
    unsigned char* smem, const int* __restrict__ cntE,
    const unsigned int* __restrict__ itemsE, int* __restrict__ offs,
    int* __restrict__ lists_e, int b) {
  int* cnt = (int*)smem;   // 256
  int* s2 = cnt + 256;     // 256
  const int istart = b * CAPE;
  const int iend = istart + cntE[b];
  const int tid = threadIdx.x;
  cnt[tid] = 0;
  __syncthreads();
  for (int i = istart + tid; i < iend; i += 256)
    atomicAdd(&cnt[itemsE[i] >> 18], 1);
  __syncthreads();
  const int v = cnt[tid];
  s2[tid] = v;
  __syncthreads();
  for (int off = 1; off < 256; off <<= 1) {
    int t = (tid >= off) ? s2[tid - off] : 0;
    __syncthreads();
    s2[tid] += t;
    __syncthreads();
  }
  const int excl = s2[tid] - v;
  const int e0 = b * 256;
  if (e0 + tid < NUM_EVENT)
    offs[NUM_USER + e0 + tid] = istart + excl + v;  // END position (padded space)
  cnt[tid] = excl;
  __syncthreads();
  for (int i = istart + tid; i < iend; i += 256) {
    const unsigned int it = itemsE[i];
    int r = atomicAdd(&cnt[it >> 18], 1);
    lists_e[istart + r] = (int)(it & 0x3FFFFu);
  }
}

// ---------------- Fused linear: y = x @ W^T + b, fp32 in, bf16-packed out ----------------
// Static stride over the unified tile list (t < TU: user, else event). Tile index
// known at loop top -> compiler hoists next tile's global loads above the barrier
// (prefetch overlap the R4 pool destroyed). W restaged at most once (monotone t).
// smem: 2 * 64*64 floats = 32768 B -> 5 blocks/CU.

__device__ __forceinline__ void linear_tiles(
    unsigned char* smem,
    const float* __restrict__ xu, const float* __restrict__ Wu,
    const float* __restrict__ bu, unsigned int* __restrict__ yu,
    const float* __restrict__ xe, const float* __restrict__ We,
    const float* __restrict__ be, unsigned int* __restrict__ ye,
    int bid, int nblocks) {
  float* xT = (float*)smem;       // xT[k][r]
  float* wT = xT + 64 * LDP;      // wT[k][c] = W[c][k]
  const int tid = threadIdx.x;
  const int r64 = tid & 63;
  const int q = tid >> 6;
  const int cg = tid & 15;  // cols cg*4..cg*4+3
  const int rg = tid >> 4;  // rows rg*4..rg*4+3

  int cur_tab = -1;
  float4 bv = make_float4(0.f, 0.f, 0.f, 0.f);

  for (int t = bid; t < NTILES; t += nblocks) {
    const int tab = (t < TU) ? 0 : 1;
    const float* x;
    const float* W;
    const float* bias;
    unsigned int* y;
    int n, tloc;
    if (tab == 0) {
      x = xu; W = Wu; bias = bu; y = yu; n = NUM_USER; tloc = t;
    } else {
      x = xe; W = We; bias = be; y = ye; n = NUM_EVENT; tloc = t - TU;
    }
    const int row0 = tloc * 64;
    const int nrows = min(64, n - row0);

    __syncthreads();  // prior-iter readers done; xT/wT reusable
    if (tab != cur_tab) {  // Stage W^T (at most twice per block).
      const int c = r64;
      const float4* wr = reinterpret_cast<const float4*>(W + (size_t)c * DDIM);
#pragma unroll
      for (int i = 0; i < 4; ++i) {
        const int kc4 = q * 4 + i;
        float4 tv = wr[kc4];
        wT[(kc4 * 4 + 0) * LDP + c] = tv.x;
        wT[(kc4 * 4 + 1) * LDP + c] = tv.y;
        wT[(kc4 * 4 + 2) * LDP + c] = tv.z;
        wT[(kc4 * 4 + 3) * LDP + c] = tv.w;
      }
      bv = reinterpret_cast<const float4*>(bias)[cg];
      cur_tab = tab;
    }
    {
      const int r = r64;
      if (r < nrows) {
        const float4* xr = reinterpret_cast<const float4*>(x + (size_t)(row0 + r) * DDIM);
#pragma unroll
        for (int i = 0; i < 4; ++i) {
          const int kc4 = q * 4 + i;
          float4 tv = xr[kc4];
          xT[(kc4 * 4 + 0) * LDP + r] = tv.x;
          xT[(kc4 * 4 + 1) * LDP + r] = tv.y;
          xT[(kc4 * 4 + 2) * LDP + r] = tv.z;
          xT[(kc4 * 4 + 3) * LDP + r] = tv.w;
        }
      }
    }
    __syncthreads();  // tiles staged

    float acc[4][4];
#pragma unroll
    for (int i = 0; i < 4; ++i) {
      acc[i][0] = bv.x; acc[i][1] = bv.y; acc[i][2] = bv.z; acc[i][3] = bv.w;
    }
#pragma unroll 8
    for (int k = 0; k < 64; ++k) {
      const float4 xv = *reinterpret_cast<const float4*>(&xT[k * LDP + rg * 4]);
      const float4 wv = *reinterpret_cast<const float4*>(&wT[k * LDP + cg * 4]);
      const float xa[4] = {xv.x, xv.y, xv.z, xv.w};
      const float wa[4] = {wv.x, wv.y, wv.z, wv.w};
#pragma unroll
      for (int i = 0; i < 4; ++i)
#pragma unroll
        for (int j = 0; j < 4; ++j) acc[i][j] += xa[i] * wa[j];
    }
#pragma unroll
    for (int i = 0; i < 4; ++i) {
      const int r = rg * 4 + i;
      if (r < nrows) {
        uint2 o = make_uint2(pack_bf2(acc[i][0], acc[i][1]),
                             pack_bf2(acc[i][2], acc[i][3]));
        reinterpret_cast<uint2*>(y + (size_t)(row0 + r) * 32)[cg] = o;
      }
    }
  }
}

// Merged dispatch: 294 build-only blocks + 986 linear-only blocks, all
// co-resident (grid = 5 blocks/CU exactly). Zero second-round tail.
__global__ __launch_bounds__(256) void build_lin_kernel(
    const int* __restrict__ cntU, const int* __restrict__ cntE,
    const unsigned int* __restrict__ itemsU,
    const unsigned int* __restrict__ itemsE, int* __restrict__ offs,
    unsigned short* __restrict__ lists_u, int* __restrict__ lists_e,
    const float* __restrict__ xu, const float* __restrict__ Wu,
    const float* __restrict__ bu, unsigned int* __restrict__ yu,
    const float* __restrict__ xe, const float* __restrict__ We,
    const float* __restrict__ be, unsigned int* __restrict__ ye) {
  __shared__ __align__(16) unsigned char smem[64 * LDP * 2 * sizeof(float)];
  const int bx = blockIdx.x;
  if (bx < NBU) {
    build_user_body(smem, cntU, itemsU, offs, lists_u, bx);
  } else if (bx < NB) {
    build_event_body(smem, cntE, itemsE, offs, lists_e, bx - NBU);
  } else {
    linear_tiles(smem, xu, Wu, bu, yu, xe, We, be, ye, bx - NB, BL_GRID - NB);
  }
}

// Layer-2 linear (standalone, depends on gather-1 output).
__global__ __launch_bounds__(256) void linear_kernel(
    const float* __restrict__ xu, const float* __restrict__ Wu,
    const float* __restrict__ bu, unsigned int* __restrict__ yu,
    const float* __restrict__ xe, const float* __restrict__ We,
    const float* __restrict__ be, unsigned int* __restrict__ ye) {
  __shared__ __align__(16) unsigned char smem[64 * LDP * 2 * sizeof(float)];
  linear_tiles(smem, xu, Wu, bu, yu, xe, We, be, ye, blockIdx.x, BL_GRID);
}

// ---------------- Fused gather aggregation (phase-sequential, prefetched) ----------------
// Eighth-wave (8 lanes) per node; lane dl holds dims 8dl..8dl+7 as one uint4.
// offs are END positions in padded item-space; the first node of each bucket
// starts at the bucket base (b*CAP).
__device__ __forceinline__ void seg_bounds(
    const int* __restrict__ offs, int obase, int node, int shift, int cap,
    int& s, int& e) {
  e = offs[obase + node];
  const int ib = node & ((1 << shift) - 1);
  s = (ib == 0) ? (node >> shift) * cap : offs[obase + node - 1];
}

template <typename IdxT>
__device__ __forceinline__ void gather_phase(
    const int* __restrict__ offs, const IdxT* __restrict__ lists,
    const uint4* __restrict__ lin_self, const uint4* __restrict__ lin_other,
    float4* __restrict__ out, int n, int obase, int shift, int cap,
    int stream_id, int nstreams, int dl) {
  int node = stream_id;
  if (node >= n) return;
  int start, end;
  seg_bounds(offs, obase, node, shift, cap, start, end);
  uint4 sv = lin_self[(size_t)node * 8 + dl];

  while (true) {
    // Prefetch next node's descriptors (issued before the gather chain).
    const int nnode = node + nstreams;
    int nstart = 0, nend = 0;
    uint4 nsv = make_uint4(0u, 0u, 0u, 0u);
    if (nnode < n) {
      seg_bounds(offs, obase, nnode, shift, cap, nstart, nend);
      nsv = lin_self[(size_t)nnode * 8 + dl];
    }

    float a0 = bf_lo(sv.x), a1 = bf_hi(sv.x);
    float a2 = bf_lo(sv.y), a3 = bf_hi(sv.y);
    float a4 = bf_lo(sv.z), a5 = bf_hi(sv.z);
    float a6 = bf_lo(sv.w), a7 = bf_hi(sv.w);
    int j = start;
    for (; j + 8 <= end; j += 8) {
      int o[8];
#pragma unroll
      for (int t = 0; t < 8; ++t) o[t] = (int)lists[j + t];
      uint4 v[8];
#pragma unroll
      for (int t = 0; t < 8; ++t) v[t] = lin_other[(size_t)o[t] * 8 + dl];
#pragma unroll
      for (int t = 0; t < 8; ++t) {
        a0 += bf_lo(v[t].x); a1 += bf_hi(v[t].x);
        a2 += bf_lo(v[t].y); a3 += bf_hi(v[t].y);
        a4 += bf_lo(v[t].z); a5 += bf_hi(v[t].z);
        a6 += bf_lo(v[t].w); a7 += bf_hi(v[t].w);
      }
    }
    for (; j + 4 <= end; j += 4) {
      int o[4];
#pragma unroll
      for (int t = 0; t < 4; ++t) o[t] = (int)lists[j + t];
      uint4 v[4];
#pragma unroll
      for (int t = 0; t < 4; ++t) v[t] = lin_other[(size_t)o[t] * 8 + dl];
#pragma unroll
      for (int t = 0; t < 4; ++t) {
        a0 += bf_lo(v[t].x); a1 += bf_hi(v[t].x);
        a2 += bf_lo(v[t].y); a3 += bf_hi(v[t].y);
        a4 += bf_lo(v[t].z); a5 += bf_hi(v[t].z);
        a6 += bf_lo(v[t].w); a7 += bf_hi(v[t].w);
      }
    }
    for (; j < end; ++j) {
      const int o0 = (int)lists[j];
      const uint4 v0 = lin_other[(size_t)o0 * 8 + dl];
      a0 += bf_lo(v0.x); a1 += bf_hi(v0.x);
      a2 += bf_lo(v0.y); a3 += bf_hi(v0.y);
      a4 += bf_lo(v0.z); a5 += bf_hi(v0.z);
      a6 += bf_lo(v0.w); a7 += bf_hi(v0.w);
    }
    const float inv = 1.0f / (float)(end - start + 1);
    out[(size_t)node * 16 + dl * 2] =
        make_float4(a0 * inv, a1 * inv, a2 * inv, a3 * inv);
    out[(size_t)node * 16 + dl * 2 + 1] =
        make_float4(a4 * inv, a5 * inv, a6 * inv, a7 * inv);

    if (nnode >= n) break;
    node = nnode;
    start = nstart;
    end = nend;
    sv = nsv;
  }
}

__global__ __launch_bounds__(256) void gather_fused_kernel(
    const int* __restrict__ offs, const unsigned short* __restrict__ lists_u,
    const int* __restrict__ lists_e, const unsigned int* __restrict__ lin_u,
    const unsigned int* __restrict__ lin_e, float* __restrict__ out_u,
    float* __restrict__ out_e) {
  const int lane = threadIdx.x & 63;
  const int dl = lane & 7;
  const int ew = ((blockIdx.x * (blockDim.x >> 6) + (threadIdx.x >> 6)) << 3) |
                 (lane >> 3);               // global eighth-wave id
  const int nstreams = GGRID * 32;          // 65536 streams, both phases
  gather_phase<unsigned short>(
      offs, lists_u, reinterpret_cast<const uint4*>(lin_u),
      reinterpret_cast<const uint4*>(lin_e), reinterpret_cast<float4*>(out_u),
      NUM_USER, 0, 11, CAPU, ew, nstreams, dl);
  gather_phase<int>(
      offs, lists_e, reinterpret_cast<const uint4*>(lin_e),
      reinterpret_cast<const uint4*>(lin_u), reinterpret_cast<float4*>(out_e),
      NUM_EVENT, NUM_USER, 8, CAPE, ew, nstreams, dl);
}

// ---------------- Launch ----------------

extern "C" void kernel_launch(void* const* d_in, const int* in_sizes, int n_in,
                              void* d_out, int out_size, void* d_ws,
                              size_t ws_size, hipStream_t stream) {
  const float* x_user = (const float*)d_in[0];
  const float* x_event = (const float*)d_in[1];
  const int* src = (const int*)d_in[2];
  const int* dst = (const int*)d_in[3];
  const float* Wu0 = (const float*)d_in[4];
  const float* bu0 = (const float*)d_in[5];
  const float* We0 = (const float*)d_in[6];
  const float* be0 = (const float*)d_in[7];
  const float* Wu1 = (const float*)d_in[8];
  const float* bu1 = (const float*)d_in[9];
  const float* We1 = (const float*)d_in[10];
  const float* be1 = (const float*)d_in[11];

  // Workspace layout (~39.6 MB, below the proven-safe 47 MB of R0-R2).
  unsigned int* lin_u = (unsigned int*)d_ws;            // 6.4M u32 = 25.6 MB
  unsigned int* lin_e = lin_u + (size_t)NUM_USER * 32;  // 1.6M u32 = 6.4 MB
  int* offs = (int*)(lin_e + (size_t)NUM_EVENT * 32);   // 250,000 = 1.0 MB
  int* cntU = offs + (NUM_USER + NUM_EVENT);            // 98
  int* cntE = cntU + NBU;                               // 196
  int* lists_e = (int*)(cntE + NBE);                    // NBE*CAPE int = 4.42 MB
  unsigned short* lists_u =
      (unsigned short*)(lists_e + (size_t)NBE * CAPE);  // NBU*CAPU u16 = 2.21 MB

  // items buffers overlay d_out (64 MB): consumed entirely inside
  // build_lin_kernel, which completes (stream order) before gather-1 writes out.
  unsigned int* itemsU = (unsigned int*)d_out;          // NBU*CAPU u32 = 4.42 MB
  unsigned int* itemsE = itemsU + (size_t)NBU * CAPU;   // NBE*CAPE u32 = 4.42 MB

  float* out_u = (float*)d_out;
  float* out_e = out_u + (size_t)NUM_USER * DDIM;

  // Zero bucket counters in one memset.
  hipMemsetAsync(cntU, 0, (NBU + NBE) * sizeof(int), stream);

  // --- CSR scatter (single pass, fixed-capacity buckets) ---
  bucket_scatter_kernel<<<NCH, 256, 0, stream>>>(src, dst, cntU, cntE, itemsU,
                                                 itemsE);

  // ---- CSR pass-B + Layer-1 linear (merged, static split, full residency) ----
  build_lin_kernel<<<BL_GRID, 256, 0, stream>>>(
      cntU, cntE, itemsU, itemsE, offs, lists_u, lists_e,
      x_user, Wu0, bu0, lin_u, x_event, We0, be0, lin_e);
  gather_fused_kernel<<<GGRID, 256, 0, stream>>>(
      offs, lists_u, lists_e, lin_u, lin_e, out_u, out_e);

  // ---- Layer 2 ----
  linear_kernel<<<BL_GRID, 256, 0, stream>>>(
      out_u, Wu1, bu1, lin_u, out_e, We1, be1, lin_e);
  gather_fused_kernel<<<GGRID, 256, 0, stream>>>(
      offs, lists_u, lists_e, lin_u, lin_e, out_u, out_e);
}